// Round 1
// baseline (600.477 us; speedup 1.0000x reference)
//
#include <hip/hip_runtime.h>
#include <math.h>

// Problem constants (DyDCNv2: B=8, C=256, O=256, H=W=64, 3x3 dconv + GN16)
#define BB 8
#define CC 256
#define OO 256
#define HH 64
#define WW 64
#define KK 9
#define HWSZ (HH*WW)        // 4096
#define CKSZ (CC*KK)        // 2304
#define NG 16               // num groups
#define OPG (OO/NG)         // 16 channels per group
#define KPBLK (KK*WW)       // 576 (k,p) pairs per row-block
#define EPSV 1e-5f

// ws layout: [0, CKSZ*OO) floats = transposed weight Wt[(c*9+k)*256 + o]
//            then B*NG*2 floats of GN stats (mean, var). ~9.4 MB total.

__global__ __launch_bounds__(256) void wt_transpose_k(
    const float* __restrict__ w, float* __restrict__ wt)
{
  int i = blockIdx.x*256 + threadIdx.x;
  if (i >= CKSZ*OO) return;
  int ck = i / OO, o = i - ck*OO;
  wt[i] = w[o*CKSZ + ck];   // weight[o][c][k] -> Wt[ck][o]
}

// One block per (b, h). 256 threads.
// Thread t: oo = t&63 owns outputs o = oo*4..oo*4+3 (float4 weight loads,
// coalesced); po = t>>6 owns positions p = po*16..po*16+15 (LDS broadcast).
__global__ __launch_bounds__(256) void dcn_gemm_k(
    const float* __restrict__ x, const float* __restrict__ off,
    const float* __restrict__ msk, const float* __restrict__ wt,
    float* __restrict__ out)
{
  int b = blockIdx.x / HH;
  int h = blockIdx.x - b*HH;

  __shared__ int   sIdx[KPBLK][4];   // 4 tap indices per (k,p)
  __shared__ float sWt [KPBLK][4];   // 4 tap weights (bilin * mask * valid)
  __shared__ float sV  [16][KPBLK];  // sampled values, 16-channel chunk

  // ---- precompute bilinear taps for all (k, p) of this row ----
  for (int t = threadIdx.x; t < KPBLK; t += 256) {
    int k = t / WW, p = t - k*WW;
    float dy = off[(((b*18) + 2*k    )*HH + h)*WW + p];
    float dx = off[(((b*18) + 2*k + 1)*HH + h)*WW + p];
    float m  = msk[(((b*KK) + k)*HH + h)*WW + p];
    float py = (float)(h + (k/3) - 1) + dy;
    float px = (float)(p + (k%3) - 1) + dx;
    float y0f = floorf(py), x0f = floorf(px);
    float wy = py - y0f, wx = px - x0f;
    int y0 = (int)y0f, x0 = (int)x0f;
    #pragma unroll
    for (int tap = 0; tap < 4; tap++) {
      int yy = y0 + (tap >> 1);
      int xx = x0 + (tap & 1);
      bool v = (yy >= 0) & (yy < HH) & (xx >= 0) & (xx < WW);
      float bw = ((tap >> 1) ? wy : 1.f - wy) * ((tap & 1) ? wx : 1.f - wx);
      sIdx[t][tap] = v ? (yy*WW + xx) : 0;
      sWt [t][tap] = v ? bw * m : 0.f;
    }
  }

  float acc[4][16];
  #pragma unroll
  for (int i = 0; i < 4; i++)
    #pragma unroll
    for (int j = 0; j < 16; j++) acc[i][j] = 0.f;

  int oo = threadIdx.x & 63;
  int po = threadIdx.x >> 6;
  const float* xb = x + (size_t)b*CC*HWSZ;

  for (int c0 = 0; c0 < CC; c0 += 16) {
    __syncthreads();   // protect sV (and first-iter taps) from prior readers
    // ---- stage: sample 16 channels into LDS ----
    #pragma unroll 4
    for (int i = 0; i < 36; i++) {            // 16*576/256 = 36
      int t = threadIdx.x + i*256;
      int c = t / KPBLK;
      int kp = t - c*KPBLK;
      const float* xc = xb + (size_t)(c0 + c)*HWSZ;
      int4   id = *(const int4*)  sIdx[kp];
      float4 bw = *(const float4*)sWt [kp];
      sV[c][kp] = bw.x*xc[id.x] + bw.y*xc[id.y]
                + bw.z*xc[id.z] + bw.w*xc[id.w];
    }
    __syncthreads();
    // ---- accumulate: acc[o4][p16] += Wt[ck][o] * V[c][k][p] ----
    for (int c = 0; c < 16; c++) {
      #pragma unroll
      for (int k = 0; k < KK; k++) {
        float4 wv = *(const float4*)&wt[(size_t)((c0 + c)*KK + k)*OO + oo*4];
        const float* vrow = &sV[c][k*WW + po*16];
        #pragma unroll
        for (int pj = 0; pj < 16; pj++) {
          float v = vrow[pj];
          acc[0][pj] = fmaf(wv.x, v, acc[0][pj]);
          acc[1][pj] = fmaf(wv.y, v, acc[1][pj]);
          acc[2][pj] = fmaf(wv.z, v, acc[2][pj]);
          acc[3][pj] = fmaf(wv.w, v, acc[3][pj]);
        }
      }
    }
  }

  // ---- write conv output (pre-GN) ----
  #pragma unroll
  for (int oi = 0; oi < 4; oi++) {
    size_t base = ((size_t)(b*OO + oo*4 + oi)*HH + h)*WW + po*16;
    #pragma unroll
    for (int q = 0; q < 4; q++) {
      float4 v = make_float4(acc[oi][q*4+0], acc[oi][q*4+1],
                             acc[oi][q*4+2], acc[oi][q*4+3]);
      *(float4*)&out[base + q*4] = v;
    }
  }
}

// One block per (b, g): reduces a contiguous 16*4096-element slab.
__global__ __launch_bounds__(1024) void gn_stats_k(
    const float* __restrict__ out, float* __restrict__ stats)
{
  int bg = blockIdx.x;
  const float4* p = (const float4*)(out + (size_t)bg*OPG*HWSZ);
  const int n4 = OPG*HWSZ/4;   // 16384
  float s1 = 0.f, s2 = 0.f;
  for (int i = threadIdx.x; i < n4; i += 1024) {
    float4 v = p[i];
    s1 += v.x + v.y + v.z + v.w;
    s2 += v.x*v.x + v.y*v.y + v.z*v.z + v.w*v.w;
  }
  #pragma unroll
  for (int o2 = 32; o2 > 0; o2 >>= 1) {
    s1 += __shfl_down(s1, o2);
    s2 += __shfl_down(s2, o2);
  }
  __shared__ float r1[16], r2[16];
  int wid = threadIdx.x >> 6, lane = threadIdx.x & 63;
  if (lane == 0) { r1[wid] = s1; r2[wid] = s2; }
  __syncthreads();
  if (threadIdx.x == 0) {
    float t1 = 0.f, t2 = 0.f;
    #pragma unroll
    for (int i = 0; i < 16; i++) { t1 += r1[i]; t2 += r2[i]; }
    const float invN = 1.f / (float)(OPG*HWSZ);
    float mean = t1 * invN;
    float var  = t2 * invN - mean*mean;
    stats[bg*2]   = mean;
    stats[bg*2+1] = var;
  }
}

__global__ __launch_bounds__(256) void gn_norm_k(
    float* __restrict__ out, const float* __restrict__ stats,
    const float* __restrict__ gamma, const float* __restrict__ beta)
{
  size_t i = (size_t)blockIdx.x*256 + threadIdx.x;   // over float4s
  const size_t n4 = (size_t)BB*OO*HWSZ/4;
  if (i >= n4) return;
  size_t base = i*4;
  int bo = (int)(base / HWSZ);
  int b = bo / OO, o = bo - b*OO;
  int g = o >> 4;
  float mean = stats[(b*NG+g)*2], var = stats[(b*NG+g)*2+1];
  float inv = rsqrtf(var + EPSV);
  float sc = gamma[o]*inv;
  float sh = beta[o] - mean*sc;
  float4 v = *(float4*)&out[base];
  v.x = v.x*sc + sh; v.y = v.y*sc + sh;
  v.z = v.z*sc + sh; v.w = v.w*sc + sh;
  *(float4*)&out[base] = v;
}

extern "C" void kernel_launch(void* const* d_in, const int* in_sizes, int n_in,
                              void* d_out, int out_size, void* d_ws, size_t ws_size,
                              hipStream_t stream) {
  const float* x      = (const float*)d_in[0];
  const float* offset = (const float*)d_in[1];
  const float* mask   = (const float*)d_in[2];
  const float* weight = (const float*)d_in[3];
  const float* gamma  = (const float*)d_in[4];
  const float* beta   = (const float*)d_in[5];
  float* out = (float*)d_out;

  float* wt    = (float*)d_ws;          // CKSZ*OO floats (~9 MB)
  float* stats = wt + (size_t)CKSZ*OO;  // B*NG*2 floats

  wt_transpose_k<<<(CKSZ*OO + 255)/256, 256, 0, stream>>>(weight, wt);
  dcn_gemm_k<<<BB*HH, 256, 0, stream>>>(x, offset, mask, wt, out);
  gn_stats_k<<<BB*NG, 1024, 0, stream>>>(out, stats);
  gn_norm_k<<<(BB*OO*HWSZ/4 + 255)/256, 256, 0, stream>>>(out, stats, gamma, beta);
}

// Round 2
// 157.134 us; speedup vs baseline: 3.8214x; 3.8214x over previous
//
#include <hip/hip_runtime.h>
#include <hip/hip_fp16.h>
#include <math.h>

// DyDCNv2: B=8, C=256, O=256, H=W=64, 3x3 modulated deformable conv + GN16
#define BB 8
#define CC 256
#define OO 256
#define HH 64
#define WW 64
#define KK 9
#define HWSZ 4096
#define CKSZ 2304
#define NG 16
#define OPG 16
#define EPSV 1e-5f

typedef _Float16 f16;
typedef f16 f16x8 __attribute__((ext_vector_type(8)));
typedef float f32x4 __attribute__((ext_vector_type(4)));

#define XH_ELEMS ((size_t)BB*HWSZ*CC)   // 8,388,608 halves (16.8 MB)
#define WH_ELEMS ((size_t)OO*CKSZ)      //   589,824 halves (1.2 MB)

// ---- x[b][c][hw] fp32  ->  xh[b][hw][c] f16 (channel-contiguous for gathers)
__global__ __launch_bounds__(256) void x_transpose_k(
    const float* __restrict__ x, __half* __restrict__ xh)
{
  int blk = blockIdx.x;
  int b = blk >> 8; int rem = blk & 255;
  int c0 = (rem >> 6) * 64; int hw0 = (rem & 63) * 64;
  __shared__ float st[64][65];
  int t = threadIdx.x;
  #pragma unroll
  for (int i = 0; i < 16; ++i) {
    int idx = t + i*256; int c = idx >> 6, w = idx & 63;
    st[c][w] = x[((size_t)(b*CC + c0 + c))*HWSZ + hw0 + w];
  }
  __syncthreads();
  #pragma unroll
  for (int i = 0; i < 8; ++i) {
    int idx = t + i*256; int r = idx >> 5, cp = idx & 31;
    __half2 v = __floats2half2_rn(st[cp*2][r], st[cp*2+1][r]);
    *(__half2*)&xh[((size_t)(b*HWSZ) + hw0 + r)*CC + c0 + cp*2] = v;
  }
}

// ---- weight[o][c][k] fp32 -> wh[o][k*256+c] f16 (K reordered k-major)
__global__ __launch_bounds__(256) void w_reorder_k(
    const float* __restrict__ w, __half* __restrict__ wh)
{
  int i = blockIdx.x*256 + threadIdx.x;   // < 589824
  int o = i / CKSZ; int kp = i - o*CKSZ;
  int kk = kp >> 8, c = kp & 255;
  wh[i] = __float2half(w[o*CKSZ + c*KK + kk]);
}

// ---- fused deformable-conv GEMM: one block per (b, 2-row strip of 128 pos)
// D[o=256][p=128] += W[o][kappa] * V[kappa][p], kappa = k*256+c, BK=64 (one k, 64 c)
__global__ __launch_bounds__(512) void dcn_mfma_k(
    const float* __restrict__ off, const float* __restrict__ msk,
    const __half* __restrict__ xh, const __half* __restrict__ wh,
    float* __restrict__ out)
{
  __shared__ __half sW[OO][72];      // 36864 B (pad 64->72: 144B stride, 2-way alias = free)
  __shared__ __half sV[128][72];     // 18432 B
  __shared__ uint    sTapOff[128][4];//  2048 B (byte offsets into xh batch slab)
  __shared__ __half2 sTapW [128][4]; //  2048 B (duplicated f16 bilinear weights * mask)

  const int t = threadIdx.x;
  const int b = blockIdx.x >> 5;
  const int h0 = (blockIdx.x & 31) * 2;
  const int lane = t & 63, wid = t >> 6;
  const int wm = wid & 3, wn = wid >> 2;     // wave -> (o-tile of 64, p-tile of 64)
  const int lr = lane & 15, lh = lane >> 4;

  f32x4 acc[4][4];
  #pragma unroll
  for (int mi = 0; mi < 4; ++mi)
    #pragma unroll
    for (int ni = 0; ni < 4; ++ni) acc[mi][ni] = (f32x4){0.f, 0.f, 0.f, 0.f};

  const char* xbase = (const char*)xh + (size_t)b * (HWSZ*CC*2);

  for (int k = 0; k < KK; ++k) {
    // ---- taps for this kernel point (single k per K-chunk) ----
    if (t < 128) {
      int p = t;
      int h = h0 + (p >> 6), w = p & 63;
      float dy = off[(((b*18) + 2*k    )*HH + h)*WW + w];
      float dx = off[(((b*18) + 2*k + 1)*HH + h)*WW + w];
      float m  = msk[(((b*KK) + k)*HH + h)*WW + w];
      float py = (float)(h + (k/3) - 1) + dy;
      float px = (float)(w + (k%3) - 1) + dx;
      float y0f = floorf(py), x0f = floorf(px);
      float wy = py - y0f, wx = px - x0f;
      int y0 = (int)y0f, x0 = (int)x0f;
      #pragma unroll
      for (int tap = 0; tap < 4; ++tap) {
        int yy = y0 + (tap >> 1), xx = x0 + (tap & 1);
        bool v = (yy >= 0) & (yy < HH) & (xx >= 0) & (xx < WW);
        float bw = ((tap >> 1) ? wy : 1.f - wy) * ((tap & 1) ? wx : 1.f - wx);
        float wgt = v ? bw * m : 0.f;
        int cy = min(max(yy, 0), HH-1), cx = min(max(xx, 0), WW-1);
        sTapOff[p][tap] = (uint)((cy*WW + cx) * (CC*2));
        sTapW [p][tap] = __float2half2_rn(wgt);
      }
    }
    for (int c0 = 0; c0 < CC; c0 += 64) {
      __syncthreads();   // prev MFMA done with sV/sW; sTap(k) visible
      // ---- sample V[p][64 c] : 8 channels per 16B gather, pk_fma combine ----
      {
        int p = t >> 2, q = t & 3;
        const uint4 offs = *(const uint4*)&sTapOff[p][0];
        __half2 w0 = sTapW[p][0], w1 = sTapW[p][1],
                w2 = sTapW[p][2], w3 = sTapW[p][3];
        const char* cb = xbase + (size_t)(c0*2);
        #pragma unroll
        for (int i = 0; i < 2; ++i) {
          int oct = q + i*4;
          int boff = oct * 16;
          uint4 r0 = *(const uint4*)(cb + offs.x + boff);
          uint4 r1 = *(const uint4*)(cb + offs.y + boff);
          uint4 r2 = *(const uint4*)(cb + offs.z + boff);
          uint4 r3 = *(const uint4*)(cb + offs.w + boff);
          const __half2* t0 = (const __half2*)&r0;
          const __half2* t1 = (const __half2*)&r1;
          const __half2* t2 = (const __half2*)&r2;
          const __half2* t3 = (const __half2*)&r3;
          __half2 o_[4];
          #pragma unroll
          for (int r = 0; r < 4; ++r)
            o_[r] = __hfma2(w0, t0[r],
                    __hfma2(w1, t1[r],
                    __hfma2(w2, t2[r], __hmul2(w3, t3[r]))));
          *(uint4*)&sV[p][oct*8] = *(uint4*)o_;
        }
      }
      // ---- stage W tile: sW[256 o][64 kappa] ----
      {
        const __half* wrow = wh + (size_t)(k*256 + c0);
        #pragma unroll
        for (int pass = 0; pass < 4; ++pass) {
          int o = (t >> 3) + pass*64;
          int seg = (t & 7) * 8;
          *(uint4*)&sW[o][seg] = *(const uint4*)&wrow[(size_t)o*CKSZ + seg];
        }
      }
      __syncthreads();   // sV/sW ready
      // ---- MFMA: 2 K-steps of 32, 16 frags/wave ----
      #pragma unroll
      for (int ks = 0; ks < 2; ++ks) {
        f16x8 a[4], bf[4];
        #pragma unroll
        for (int mi = 0; mi < 4; ++mi)
          a[mi] = *(const f16x8*)&sW[wm*64 + mi*16 + lr][ks*32 + lh*8];
        #pragma unroll
        for (int ni = 0; ni < 4; ++ni)
          bf[ni] = *(const f16x8*)&sV[wn*64 + ni*16 + lr][ks*32 + lh*8];
        #pragma unroll
        for (int mi = 0; mi < 4; ++mi)
          #pragma unroll
          for (int ni = 0; ni < 4; ++ni)
            acc[mi][ni] = __builtin_amdgcn_mfma_f32_16x16x32_f16(
                a[mi], bf[ni], acc[mi][ni], 0, 0, 0);
      }
    }
  }
  // ---- epilogue: D row=o (lane>>4)*4+j, col=p lane&15 ----
  #pragma unroll
  for (int mi = 0; mi < 4; ++mi) {
    #pragma unroll
    for (int ni = 0; ni < 4; ++ni) {
      int o  = wm*64 + mi*16 + lh*4;
      int pp = wn*64 + ni*16 + lr;
      size_t base = ((size_t)(b*OO + o))*HWSZ + h0*WW + pp;
      #pragma unroll
      for (int j = 0; j < 4; ++j)
        out[base + (size_t)j*HWSZ] = acc[mi][ni][j];
    }
  }
}

// ---- GroupNorm: stats over each (b, group of 16 o) slab ----
__global__ __launch_bounds__(1024) void gn_stats_k(
    const float* __restrict__ out, float* __restrict__ stats)
{
  int bg = blockIdx.x;
  const float4* p = (const float4*)(out + (size_t)bg*OPG*HWSZ);
  const int n4 = OPG*HWSZ/4;   // 16384
  float s1 = 0.f, s2 = 0.f;
  for (int i = threadIdx.x; i < n4; i += 1024) {
    float4 v = p[i];
    s1 += v.x + v.y + v.z + v.w;
    s2 += v.x*v.x + v.y*v.y + v.z*v.z + v.w*v.w;
  }
  #pragma unroll
  for (int o2 = 32; o2 > 0; o2 >>= 1) {
    s1 += __shfl_down(s1, o2);
    s2 += __shfl_down(s2, o2);
  }
  __shared__ float r1[16], r2[16];
  int wid = threadIdx.x >> 6, lane = threadIdx.x & 63;
  if (lane == 0) { r1[wid] = s1; r2[wid] = s2; }
  __syncthreads();
  if (threadIdx.x == 0) {
    float t1 = 0.f, t2 = 0.f;
    #pragma unroll
    for (int i = 0; i < 16; i++) { t1 += r1[i]; t2 += r2[i]; }
    const float invN = 1.f / (float)(OPG*HWSZ);
    float mean = t1 * invN;
    float var  = t2 * invN - mean*mean;
    stats[bg*2]   = mean;
    stats[bg*2+1] = var;
  }
}

__global__ __launch_bounds__(256) void gn_norm_k(
    float* __restrict__ out, const float* __restrict__ stats,
    const float* __restrict__ gamma, const float* __restrict__ beta)
{
  size_t i = (size_t)blockIdx.x*256 + threadIdx.x;   // over float4s
  const size_t n4 = (size_t)BB*OO*HWSZ/4;
  if (i >= n4) return;
  size_t base = i*4;
  int bo = (int)(base / HWSZ);
  int b = bo / OO, o = bo - b*OO;
  int g = o >> 4;
  float mean = stats[(b*NG+g)*2], var = stats[(b*NG+g)*2+1];
  float inv = rsqrtf(var + EPSV);
  float sc = gamma[o]*inv;
  float sh = beta[o] - mean*sc;
  float4 v = *(float4*)&out[base];
  v.x = v.x*sc + sh; v.y = v.y*sc + sh;
  v.z = v.z*sc + sh; v.w = v.w*sc + sh;
  *(float4*)&out[base] = v;
}

extern "C" void kernel_launch(void* const* d_in, const int* in_sizes, int n_in,
                              void* d_out, int out_size, void* d_ws, size_t ws_size,
                              hipStream_t stream) {
  const float* x      = (const float*)d_in[0];
  const float* offset = (const float*)d_in[1];
  const float* mask   = (const float*)d_in[2];
  const float* weight = (const float*)d_in[3];
  const float* gamma  = (const float*)d_in[4];
  const float* beta   = (const float*)d_in[5];
  float* out = (float*)d_out;

  __half* xh = (__half*)d_ws;                 // 16.8 MB
  __half* wh = xh + XH_ELEMS;                 //  1.2 MB
  float* stats = (float*)(wh + WH_ELEMS);     //  1 KB

  x_transpose_k<<<BB*4*64, 256, 0, stream>>>(x, xh);
  w_reorder_k<<<(int)(WH_ELEMS/256), 256, 0, stream>>>(weight, wh);
  dcn_mfma_k<<<BB*32, 512, 0, stream>>>(offset, mask, xh, wh, out);
  gn_stats_k<<<BB*NG, 1024, 0, stream>>>(out, stats);
  gn_norm_k<<<(int)((size_t)BB*OO*HWSZ/4 + 255)/256, 256, 0, stream>>>(out, stats, gamma, beta);
}

// Round 3
// 97.423 us; speedup vs baseline: 6.1636x; 1.6129x over previous
//
#include <hip/hip_runtime.h>
#include <hip/hip_fp16.h>
#include <math.h>

// DyDCNv2: B=8, C=256, O=256, H=W=64, 3x3 modulated deformable conv + GN16
#define BB 8
#define CC 256
#define OO 256
#define HH 64
#define WW 64
#define KK 9
#define HWSZ 4096
#define CKSZ 2304
#define NG 16
#define OPG 16
#define EPSV 1e-5f

typedef _Float16 f16;
typedef f16 f16x8 __attribute__((ext_vector_type(8)));
typedef float f32x4 __attribute__((ext_vector_type(4)));

#define XH_ELEMS ((size_t)BB*HWSZ*CC)    // 8,388,608 halves (16.8 MB)
#define WH_ELEMS ((size_t)OO*CKSZ)       //   589,824 halves (1.2 MB)
#define POUT_ELEMS ((size_t)BB*OO*HWSZ)  // 8,388,608 halves per K-half
#define WS_NEED_SPLIT ((XH_ELEMS + WH_ELEMS + 2*POUT_ELEMS)*2 + 1024)

__device__ __forceinline__ void gload_lds16(const void* g, void* l) {
  __builtin_amdgcn_global_load_lds(
      (const __attribute__((address_space(1))) void*)g,
      (__attribute__((address_space(3))) void*)l, 16, 0, 0);
}

// ---- x[b][c][hw] fp32  ->  xh[b][hw][c] f16 (channel-contiguous for gathers)
__global__ __launch_bounds__(256) void x_transpose_k(
    const float* __restrict__ x, __half* __restrict__ xh)
{
  int blk = blockIdx.x;
  int b = blk >> 8; int rem = blk & 255;
  int c0 = (rem >> 6) * 64; int hw0 = (rem & 63) * 64;
  __shared__ float st[64][65];
  int t = threadIdx.x;
  #pragma unroll
  for (int i = 0; i < 16; ++i) {
    int idx = t + i*256; int c = idx >> 6, w = idx & 63;
    st[c][w] = x[((size_t)(b*CC + c0 + c))*HWSZ + hw0 + w];
  }
  __syncthreads();
  #pragma unroll
  for (int i = 0; i < 8; ++i) {
    int idx = t + i*256; int r = idx >> 5, cp = idx & 31;
    __half2 v = __floats2half2_rn(st[cp*2][r], st[cp*2+1][r]);
    *(__half2*)&xh[((size_t)(b*HWSZ) + hw0 + r)*CC + c0 + cp*2] = v;
  }
}

// ---- weight[o][c][k] fp32 -> wh[o][k*256+c] f16 (K reordered k-major)
__global__ __launch_bounds__(256) void w_reorder_k(
    const float* __restrict__ w, __half* __restrict__ wh)
{
  int i = blockIdx.x*256 + threadIdx.x;   // < 589824
  int o = i / CKSZ; int kp = i - o*CKSZ;
  int kk = kp >> 8, c = kp & 255;
  wh[i] = __float2half(w[o*CKSZ + c*KK + kk]);
}

// ---- fused deformable-conv GEMM ----
// SPLIT=1: grid 512 = (b 8) x (kh 2) x (strip 32); each block does 18 of the
//          36 (k,c0) chunks, writes f16 partials. 2 blocks/CU co-resident.
// SPLIT=0: grid 256, all 36 chunks, writes f32 out directly (ws fallback).
// LDS: sW linear [256][64] via global_load_lds (XOR-swizzled source),
//      sV linear [128][64] XOR-swizzled writes; seg ^= (row&7) involution.
template<int SPLIT>
__global__ __launch_bounds__(512, 4) void dcn_mfma_k(
    const float* __restrict__ off, const float* __restrict__ msk,
    const __half* __restrict__ xh, const __half* __restrict__ wh,
    float* __restrict__ out, __half* __restrict__ pout)
{
  __shared__ __half sWl[OO*64];      // 32768 B
  __shared__ __half sVl[128*64];     // 16384 B
  __shared__ uint    sTapOff[128][4];//  2048 B
  __shared__ __half2 sTapW [128][4]; //  2048 B

  const int t = threadIdx.x;
  const int b = blockIdx.x & 7;          // XCD-pin: one batch per XCD
  const int rest = blockIdx.x >> 3;
  const int kh    = SPLIT ? (rest & 1) : 0;
  const int strip = SPLIT ? (rest >> 1) : rest;
  const int h0 = strip * 2;
  const int cstart = SPLIT ? kh*18 : 0;
  const int nch    = SPLIT ? 18 : 36;

  const int lane = t & 63, wid = t >> 6;
  const int wm = wid & 3, wn = wid >> 2;     // wave -> (o-tile 64, p-tile 64)
  const int lr = lane & 15, lh = lane >> 4;

  f32x4 acc[4][4];
  #pragma unroll
  for (int mi = 0; mi < 4; ++mi)
    #pragma unroll
    for (int ni = 0; ni < 4; ++ni) acc[mi][ni] = (f32x4){0.f, 0.f, 0.f, 0.f};

  const char* xbase = (const char*)xh + (size_t)b * (HWSZ*CC*2);
  int kprev = -1;

  for (int cc = cstart; cc < cstart + nch; ++cc) {
    const int k = cc >> 2;
    const int c0 = (cc & 3) << 6;
    __syncthreads();   // prev MFMA done reading sWl/sVl

    if (k != kprev) {  // taps for new kernel point (uniform branch)
      kprev = k;
      if (t < 128) {
        int p = t;
        int h = h0 + (p >> 6), w = p & 63;
        float dy = off[(((b*18) + 2*k    )*HH + h)*WW + w];
        float dx = off[(((b*18) + 2*k + 1)*HH + h)*WW + w];
        float m  = msk[(((b*KK) + k)*HH + h)*WW + w];
        float py = (float)(h + (k/3) - 1) + dy;
        float px = (float)(w + (k%3) - 1) + dx;
        float y0f = floorf(py), x0f = floorf(px);
        float wy = py - y0f, wx = px - x0f;
        int y0 = (int)y0f, x0 = (int)x0f;
        #pragma unroll
        for (int tap = 0; tap < 4; ++tap) {
          int yy = y0 + (tap >> 1), xx = x0 + (tap & 1);
          bool v = (yy >= 0) & (yy < HH) & (xx >= 0) & (xx < WW);
          float bw = ((tap >> 1) ? wy : 1.f - wy) * ((tap & 1) ? wx : 1.f - wx);
          float wgt = v ? bw * m : 0.f;
          int cy = min(max(yy, 0), HH-1), cx = min(max(xx, 0), WW-1);
          sTapOff[p][tap] = (uint)((cy*WW + cx) * (CC*2));
          sTapW [p][tap] = __float2half2_rn(wgt);
        }
      }
      __syncthreads();  // taps visible to gather
    }

    // ---- issue W-tile stage first (async global->LDS, latency overlaps gather)
    {
      #pragma unroll
      for (int i = 0; i < 4; ++i) {
        int idx = i*512 + t;
        int o = idx >> 3, s = idx & 7;
        const __half* g = wh + (size_t)o*CKSZ + k*256 + c0 + ((s ^ (o & 7)) << 3);
        char* ldsbase = (char*)sWl + (size_t)(i*512 + (t & ~63))*16;
        gload_lds16(g, ldsbase);
      }
    }
    // ---- sample V[p][64 c]: 8 channels per 16B gather, hfma2 combine ----
    {
      int p = t >> 2, q = t & 3;
      const uint4 offs = *(const uint4*)&sTapOff[p][0];
      __half2 w0 = sTapW[p][0], w1 = sTapW[p][1],
              w2 = sTapW[p][2], w3 = sTapW[p][3];
      const char* cb = xbase + (size_t)(c0*2);
      #pragma unroll
      for (int i = 0; i < 2; ++i) {
        int oct = q + i*4;
        int boff = oct * 16;
        uint4 r0 = *(const uint4*)(cb + offs.x + boff);
        uint4 r1 = *(const uint4*)(cb + offs.y + boff);
        uint4 r2 = *(const uint4*)(cb + offs.z + boff);
        uint4 r3 = *(const uint4*)(cb + offs.w + boff);
        const __half2* t0 = (const __half2*)&r0;
        const __half2* t1 = (const __half2*)&r1;
        const __half2* t2 = (const __half2*)&r2;
        const __half2* t3 = (const __half2*)&r3;
        __half2 o_[4];
        #pragma unroll
        for (int r = 0; r < 4; ++r)
          o_[r] = __hfma2(w0, t0[r],
                  __hfma2(w1, t1[r],
                  __hfma2(w2, t2[r], __hmul2(w3, t3[r]))));
        int s = oct ^ (p & 7);
        *(uint4*)&sVl[p*64 + s*8] = *(uint4*)o_;
      }
    }
    __syncthreads();   // sV written; vmcnt drained for sW (compiler-inserted)
    // ---- MFMA: 2 K-steps of 32, 16 frags/wave ----
    #pragma unroll
    for (int ks = 0; ks < 2; ++ks) {
      f16x8 a[4], bfr[4];
      #pragma unroll
      for (int mi = 0; mi < 4; ++mi) {
        int r = wm*64 + mi*16 + lr;
        a[mi] = *(const f16x8*)&sWl[r*64 + (((ks*4 + lh) ^ (r & 7)) << 3)];
      }
      #pragma unroll
      for (int ni = 0; ni < 4; ++ni) {
        int r = wn*64 + ni*16 + lr;
        bfr[ni] = *(const f16x8*)&sVl[r*64 + (((ks*4 + lh) ^ (r & 7)) << 3)];
      }
      #pragma unroll
      for (int mi = 0; mi < 4; ++mi)
        #pragma unroll
        for (int ni = 0; ni < 4; ++ni)
          acc[mi][ni] = __builtin_amdgcn_mfma_f32_16x16x32_f16(
              a[mi], bfr[ni], acc[mi][ni], 0, 0, 0);
    }
  }

  // ---- epilogue: D row=o ((lane>>4)*4+j), col=p (lane&15) ----
  #pragma unroll
  for (int mi = 0; mi < 4; ++mi) {
    #pragma unroll
    for (int ni = 0; ni < 4; ++ni) {
      int ob = wm*64 + mi*16 + lh*4;
      int pp = wn*64 + ni*16 + lr;
      if (SPLIT) {
        __half* dst = pout + (size_t)kh*POUT_ELEMS;
        #pragma unroll
        for (int j = 0; j < 4; ++j)
          dst[((size_t)(b*OO + ob + j))*HWSZ + h0*WW + pp] =
              __float2half(acc[mi][ni][j]);
      } else {
        #pragma unroll
        for (int j = 0; j < 4; ++j)
          out[((size_t)(b*OO + ob + j))*HWSZ + h0*WW + pp] = acc[mi][ni][j];
      }
    }
  }
}

// ---- split path: sum two f16 partials -> f32 out, fused GN stats ----
// one block per (b,g): 65536 contiguous elements
__global__ __launch_bounds__(1024) void reduce_stats_k(
    const __half* __restrict__ p0, const __half* __restrict__ p1,
    float* __restrict__ out, float* __restrict__ stats)
{
  int bg = blockIdx.x;   // 0..127
  size_t base = (size_t)bg * (OPG*HWSZ);
  float s1 = 0.f, s2 = 0.f;
  for (int i = threadIdx.x; i < OPG*HWSZ/8; i += 1024) {
    size_t o8 = base + (size_t)i*8;
    uint4 ua = *(const uint4*)(p0 + o8);
    uint4 ub = *(const uint4*)(p1 + o8);
    const __half2* ah = (const __half2*)&ua;
    const __half2* bh = (const __half2*)&ub;
    float r[8];
    #pragma unroll
    for (int j = 0; j < 4; ++j) {
      float2 fa = __half22float2(ah[j]);
      float2 fb = __half22float2(bh[j]);
      r[2*j]   = fa.x + fb.x;
      r[2*j+1] = fa.y + fb.y;
    }
    #pragma unroll
    for (int j = 0; j < 8; ++j) { s1 += r[j]; s2 += r[j]*r[j]; }
    *(float4*)(out + o8)     = make_float4(r[0], r[1], r[2], r[3]);
    *(float4*)(out + o8 + 4) = make_float4(r[4], r[5], r[6], r[7]);
  }
  #pragma unroll
  for (int o2 = 32; o2 > 0; o2 >>= 1) {
    s1 += __shfl_down(s1, o2);
    s2 += __shfl_down(s2, o2);
  }
  __shared__ float r1[16], r2[16];
  int wd = threadIdx.x >> 6, lane = threadIdx.x & 63;
  if (lane == 0) { r1[wd] = s1; r2[wd] = s2; }
  __syncthreads();
  if (threadIdx.x == 0) {
    float t1 = 0.f, t2 = 0.f;
    #pragma unroll
    for (int i = 0; i < 16; i++) { t1 += r1[i]; t2 += r2[i]; }
    const float invN = 1.f / (float)(OPG*HWSZ);
    float mean = t1 * invN;
    float var  = t2 * invN - mean*mean;
    stats[bg*2]   = mean;
    stats[bg*2+1] = var;
  }
}

// ---- fallback GN stats (non-split path) ----
__global__ __launch_bounds__(1024) void gn_stats_k(
    const float* __restrict__ out, float* __restrict__ stats)
{
  int bg = blockIdx.x;
  const float4* p = (const float4*)(out + (size_t)bg*OPG*HWSZ);
  const int n4 = OPG*HWSZ/4;
  float s1 = 0.f, s2 = 0.f;
  for (int i = threadIdx.x; i < n4; i += 1024) {
    float4 v = p[i];
    s1 += v.x + v.y + v.z + v.w;
    s2 += v.x*v.x + v.y*v.y + v.z*v.z + v.w*v.w;
  }
  #pragma unroll
  for (int o2 = 32; o2 > 0; o2 >>= 1) {
    s1 += __shfl_down(s1, o2);
    s2 += __shfl_down(s2, o2);
  }
  __shared__ float r1[16], r2[16];
  int wd = threadIdx.x >> 6, lane = threadIdx.x & 63;
  if (lane == 0) { r1[wd] = s1; r2[wd] = s2; }
  __syncthreads();
  if (threadIdx.x == 0) {
    float t1 = 0.f, t2 = 0.f;
    #pragma unroll
    for (int i = 0; i < 16; i++) { t1 += r1[i]; t2 += r2[i]; }
    const float invN = 1.f / (float)(OPG*HWSZ);
    float mean = t1 * invN;
    float var  = t2 * invN - mean*mean;
    stats[bg*2]   = mean;
    stats[bg*2+1] = var;
  }
}

__global__ __launch_bounds__(256) void gn_norm_k(
    float* __restrict__ out, const float* __restrict__ stats,
    const float* __restrict__ gamma, const float* __restrict__ beta)
{
  size_t i = (size_t)blockIdx.x*256 + threadIdx.x;   // over float4s
  const size_t n4 = (size_t)BB*OO*HWSZ/4;
  if (i >= n4) return;
  size_t base = i*4;
  int bo = (int)(base / HWSZ);
  int b = bo / OO, o = bo - b*OO;
  int g = o >> 4;
  float mean = stats[(b*NG+g)*2], var = stats[(b*NG+g)*2+1];
  float inv = rsqrtf(var + EPSV);
  float sc = gamma[o]*inv;
  float sh = beta[o] - mean*sc;
  float4 v = *(float4*)&out[base];
  v.x = v.x*sc + sh; v.y = v.y*sc + sh;
  v.z = v.z*sc + sh; v.w = v.w*sc + sh;
  *(float4*)&out[base] = v;
}

extern "C" void kernel_launch(void* const* d_in, const int* in_sizes, int n_in,
                              void* d_out, int out_size, void* d_ws, size_t ws_size,
                              hipStream_t stream) {
  const float* x      = (const float*)d_in[0];
  const float* offset = (const float*)d_in[1];
  const float* mask   = (const float*)d_in[2];
  const float* weight = (const float*)d_in[3];
  const float* gamma  = (const float*)d_in[4];
  const float* beta   = (const float*)d_in[5];
  float* out = (float*)d_out;

  __half* xh   = (__half*)d_ws;
  __half* wh   = xh + XH_ELEMS;
  __half* pout = wh + WH_ELEMS;
  float* stats = (float*)(pout + 2*POUT_ELEMS);
  float* stats_fb = (float*)(wh + WH_ELEMS);

  x_transpose_k<<<BB*4*64, 256, 0, stream>>>(x, xh);
  w_reorder_k<<<(int)(WH_ELEMS/256), 256, 0, stream>>>(weight, wh);

  if (ws_size >= WS_NEED_SPLIT) {
    dcn_mfma_k<1><<<512, 512, 0, stream>>>(offset, mask, xh, wh, out, pout);
    reduce_stats_k<<<BB*NG, 1024, 0, stream>>>(pout, pout + POUT_ELEMS, out, stats);
    gn_norm_k<<<(int)((size_t)BB*OO*HWSZ/4 + 255)/256, 256, 0, stream>>>(
        out, stats, gamma, beta);
  } else {
    dcn_mfma_k<0><<<256, 512, 0, stream>>>(offset, mask, xh, wh, out, (__half*)nullptr);
    gn_stats_k<<<BB*NG, 1024, 0, stream>>>(out, stats_fb);
    gn_norm_k<<<(int)((size_t)BB*OO*HWSZ/4 + 255)/256, 256, 0, stream>>>(
        out, stats_fb, gamma, beta);
  }
}